// Round 11
// baseline (150.692 us; speedup 1.0000x reference)
//
#include <hip/hip_runtime.h>
#include <hip/hip_bf16.h>

typedef __bf16 bf16x8 __attribute__((ext_vector_type(8)));
typedef _Float16 f16x8 __attribute__((ext_vector_type(8)));
typedef _Float16 f16x2 __attribute__((ext_vector_type(2)));
typedef float  f32x4  __attribute__((ext_vector_type(4)));
typedef int    i32x4  __attribute__((ext_vector_type(4)));
typedef unsigned short u16x8 __attribute__((ext_vector_type(8)));
typedef unsigned short us4   __attribute__((ext_vector_type(4)));

#define HH    8
#define NN    4096
#define FIN   512
#define FOUT  64
#define ALPHA 0.2f

// ---------------------------------------------------------------------------
// k0: W[h][f][o] (fp32) -> WT2 TILED bf16: [h][kb][o][km], f = kb*32+km.
// Tiled so k_prep's b-loads are contiguous-1KB per instruction.
// Wsrc loads are single-use -> nontemporal (keep L2 for reused data).
// ---------------------------------------------------------------------------
__global__ __launch_bounds__(256) void k_transpose_w(
    const float* __restrict__ Wsrc, __hip_bfloat16* __restrict__ WT) {
    __shared__ __hip_bfloat16 lt[64][65];
    const int h  = blockIdx.x >> 3;
    const int f0 = (blockIdx.x & 7) * 64;
    const int tid = threadIdx.x;
#pragma unroll
    for (int p = 0; p < 16; ++p) {
        int f = p * 4 + (tid >> 6);
        int o = tid & 63;
        float w = __builtin_nontemporal_load(
            Wsrc + ((size_t)h * FIN + f0 + f) * FOUT + o);
        lt[f][o] = __float2bfloat16(w);
    }
    __syncthreads();
#pragma unroll
    for (int p = 0; p < 16; ++p) {
        int o = p * 4 + (tid >> 6);
        int f = tid & 63;          // local f; global f = f0 + f
        int gf = f0 + f;
        // WT2[h][kb][o][km]: ((h*16 + gf/32)*64 + o)*32 + gf%32
        WT[(((size_t)h * 16 + (gf >> 5)) * 64 + o) * 32 + (gf & 31)] = lt[f][o];
    }
}

// ---------------------------------------------------------------------------
// k_prep: FUSED adjacency bit-pack + projection (R17 structure, confirmed).
// R22: single-use streams marked nontemporal — adj loads (64 MB, read once),
// mask stores (read by k_flash later, via L3/HBM anyway due to cross-XCD
// non-coherence), feat loads (each row read once). WT2 reads stay cached
// (reused by 128 blocks). Rationale: k_flash FETCH=18.2 MB vs 6.5 MB unique
// showed WhT being thrashed out of L2 by streaming data; keep L2 for reuse.
// ---------------------------------------------------------------------------
__global__ __launch_bounds__(256) void k_prep(
    const int* __restrict__ adj,
    unsigned* __restrict__ maskdst, int mstride,
    const float* __restrict__ feat,
    const __hip_bfloat16* __restrict__ WT,
    const float* __restrict__ a_src,
    const float* __restrict__ a_dst,
    unsigned short* __restrict__ WhT,
    float* __restrict__ srcv,
    unsigned short* __restrict__ Ebf, unsigned short* __restrict__ Fbf) {
    __shared__ alignas(16) __hip_bfloat16 lfeat[32][520];

    const int tid = threadIdx.x;

    if (blockIdx.x >= 256) {   // ---- pack path ----
        const int b = blockIdx.x - 256;
        const size_t base = (size_t)b * 8192;
        unsigned* lbuf = (unsigned*)&lfeat[0][0];    // 1 KB alias
        const int l = tid & 63;
        const int w = tid >> 6;
        unsigned keep = 0;
#pragma unroll
        for (int i = 0; i < 8; ++i) {
            i32x4 v = __builtin_nontemporal_load(
                (const i32x4*)(adj + base + (size_t)(i * 256 + tid) * 4));
            unsigned nib = (unsigned)(v.x > 0) | ((unsigned)(v.y > 0) << 1)
                         | ((unsigned)(v.z > 0) << 2) | ((unsigned)(v.w > 0) << 3);
            unsigned vv = nib << ((l & 7) * 4);
            vv |= __shfl_xor(vv, 1);
            vv |= __shfl_xor(vv, 2);
            vv |= __shfl_xor(vv, 4);
            keep = ((l & 7) == i) ? vv : keep;
        }
        // lane l holds dword (i = l&7, d = l>>3): index = (l&7)*32 + w*8 + (l>>3)
        lbuf[(l & 7) * 32 + w * 8 + (l >> 3)] = keep;
        __syncthreads();
        __builtin_nontemporal_store(lbuf[tid], maskdst + (size_t)b * mstride + tid);
        return;
    }

    // ---- projection path ----
    const int pb   = blockIdx.x;
    const int tile = pb & 127;            // 32 rows per block
    const int hgy  = pb >> 7;             // 0..1

#pragma unroll
    for (int p = 0; p < 16; ++p) {
        int idx  = p * 256 + tid;
        int row  = idx >> 7;
        int col4 = (idx & 127) * 4;
        f32x4 f = __builtin_nontemporal_load(
            (const f32x4*)(feat + (size_t)(tile * 32 + row) * FIN + col4));
        __hip_bfloat16* dst = &lfeat[row][col4];
        dst[0] = __float2bfloat16(f[0]); dst[1] = __float2bfloat16(f[1]);
        dst[2] = __float2bfloat16(f[2]); dst[3] = __float2bfloat16(f[3]);
    }
    __syncthreads();

    const int h     = hgy * 4 + (tid >> 6);
    const int lane  = tid & 63;
    const int row16 = lane & 15;
    const int quad  = lane >> 4;

    // tiled WT2 base for head h: 16 kb-tiles x 2048 elements
    const unsigned short* WTu = (const unsigned short*)WT + (size_t)h * 16 * 2048;

    f32x4 acc[2][4] = {};
    for (int k0 = 0; k0 < FIN; k0 += 32) {
        bf16x8 a0 = *(const bf16x8*)&lfeat[row16][k0 + quad * 8];
        bf16x8 a1 = *(const bf16x8*)&lfeat[16 + row16][k0 + quad * 8];
        const unsigned short* wkb = WTu + (size_t)(k0 >> 5) * 2048;
#pragma unroll
        for (int ot = 0; ot < 4; ++ot) {
            bf16x8 b = *(const bf16x8*)(wkb + (ot * 16 + row16) * 32 + quad * 8);
            acc[0][ot] = __builtin_amdgcn_mfma_f32_16x16x32_bf16(a0, b, acc[0][ot], 0, 0, 0);
            acc[1][ot] = __builtin_amdgcn_mfma_f32_16x16x32_bf16(a1, b, acc[1][ot], 0, 0, 0);
        }
    }

    // tiled WhT store: [h][jb=tile][o][jm], jm = g*16 + quad*4 + r
#pragma unroll
    for (int g = 0; g < 2; ++g)
#pragma unroll
        for (int ot = 0; ot < 4; ++ot) {
            us4 u;
#pragma unroll
            for (int r = 0; r < 4; ++r)
                u[r] = __builtin_bit_cast(unsigned short, (_Float16)acc[g][ot][r]);
            *(us4*)(WhT + (((size_t)(h * 128 + tile) * 64 + ot * 16 + row16) << 5)
                        + g * 16 + quad * 4) = u;
        }

    float asv[4], adv[4];
#pragma unroll
    for (int ot = 0; ot < 4; ++ot) {
        asv[ot] = a_src[h * FOUT + ot * 16 + row16];
        adv[ot] = a_dst[h * FOUT + ot * 16 + row16];
    }
#pragma unroll
    for (int g = 0; g < 2; ++g)
#pragma unroll
        for (int r = 0; r < 4; ++r) {
            float ss = 0.f, dd = 0.f;
#pragma unroll
            for (int ot = 0; ot < 4; ++ot) {
                ss += acc[g][ot][r] * asv[ot];
                dd += acc[g][ot][r] * adv[ot];
            }
            ss += __shfl_xor(ss, 1); ss += __shfl_xor(ss, 2);
            ss += __shfl_xor(ss, 4); ss += __shfl_xor(ss, 8);
            dd += __shfl_xor(dd, 1); dd += __shfl_xor(dd, 2);
            dd += __shfl_xor(dd, 4); dd += __shfl_xor(dd, 8);
            if (row16 == 0) {
                int n = tile * 32 + g * 16 + quad * 4 + r;
                srcv[h * NN + n] = ss;
                _Float16 e = (_Float16)__expf(dd);
                _Float16 f = (_Float16)__expf(ALPHA * dd);
                Ebf[h * NN + n] = __builtin_bit_cast(unsigned short, e);
                Fbf[h * NN + n] = __builtin_bit_cast(unsigned short, f);
            }
        }
}

// ---------------------------------------------------------------------------
// k_flash v11 = R6 (proven best, 143.3 total) + nontemporal streams.
// R22 theory: the one hard anomaly left is FETCH_SIZE = 18.2 MB vs ~6.5 MB
// unique -> ~12 MB of WhT re-fetched from HBM. Mechanism: grid (64,8) maps
// all 8 heads of a tile-octet to one XCD (linear id h*64+t -> XCD t%8), so
// per-XCD set = WhT 4 MB + mask 1 MB + E/F > 4 MB L2; the single-use mask
// STREAM continuously evicts reused WhT lines -> mid-loop HBM misses
// (~900 cyc) beyond the ping-pong's ~350-cyc slack. R10 (head-per-XCD)
// fixed capacity but broke mask dedup -> null, consistent.
// Fix: mark single-use traffic nontemporal so L2 keeps only reuse:
//   - mask staging loads (128 KB/block, LDS-staged, never re-read)
//   - final out stores (write-once)
// Everything else byte-identical to R6: 64-row tiles, grid (64,8), 256 thr,
// 4 j-segs x 1024 j, ping-pong 1-deep prefetch, seg+parity stagger, setprio,
// launch_bounds(256,3), 2-buf/4-sync reduction, f16 packed score pipeline.
// Predicted: FETCH 18.2 -> 7-9 MB, k_flash 42.6 -> 27-34 µs. If FETCH drops
// but dur flat: stall is counter-invisible -> declare floor next round.
// ---------------------------------------------------------------------------
__global__ __launch_bounds__(256, 3) void k_flash(
    const unsigned* __restrict__ maskp, int mstride,
    const float* __restrict__ srcv,
    const unsigned short* __restrict__ Ebf,
    const unsigned short* __restrict__ Fbf,
    const unsigned short* __restrict__ WhT,
    float* __restrict__ out) {
    __shared__ float st[2][64 * 68];     // 34816 B; mask (33792 B) aliases st
    __shared__ float lds_l[2][64];

    unsigned* lmask = (unsigned*)&st[0][0];   // [64 rows][132 dwords]

    const int tid   = threadIdx.x;
    const int seg   = tid >> 6;               // 0..3, 1024 j each
    const int lane  = tid & 63;
    const int row16 = lane & 15;
    const int quad  = lane >> 4;
    const int shl   = quad * 8;
    const int tile  = blockIdx.x;             // 64 rows
    const int h     = blockIdx.y;

    // ---- stage mask bits for 64 rows (32 row-pair chunks, 1 KB each)
    //      nontemporal: single-use stream, don't evict WhT from L2
#pragma unroll
    for (int p = 0; p < 8; ++p) {
        int tt = tid + p * 256;
        int c  = tt >> 6;                     // chunk 0..31
        int o  = (tt & 63) * 16;              // byte offset in chunk
        i32x4 v = __builtin_nontemporal_load(
            (const i32x4*)((const char*)maskp
                           + ((size_t)(tile * 32 + c) * mstride) * 4 + o));
        int row = c * 2 + (o >> 9);
        int dw  = (o & 511) >> 2;
        *(i32x4*)&lmask[row * 132 + dw] = v;
    }
    __syncthreads();

    // per-row src factors, packed f16x2 (both halves equal)
    f16x2 Es2[4], Fs2[4];
#pragma unroll
    for (int g = 0; g < 4; ++g) {
        float si = srcv[h * NN + tile * 64 + g * 16 + row16];
        _Float16 e = (_Float16)__expf(si);
        _Float16 f = (_Float16)__expf(ALPHA * si);
        Es2[g][0] = e; Es2[g][1] = e;
        Fs2[g][0] = f; Fs2[g][1] = f;
    }
    const int mbase = row16 * 132 + seg * 32;   // + g*2112 + t

    const unsigned short* Eb  = Ebf + h * NN + seg * 1024;
    const unsigned short* Fb  = Fbf + h * NN + seg * 1024;
    const unsigned short* whh = WhT + (size_t)h * FOUT * NN;   // tiled base

    f32x4 acc[4][4] = {};
    float lsum[4]   = {};
    const f16x2 ones2 = {(_Float16)1.0f, (_Float16)1.0f};

    auto LOAD = [&](f16x8& ev_, f16x8& fv_, f16x8* b_, unsigned* m_, int tt) {
        const int jj = tt * 32 + shl;
        const size_t jb = (size_t)(seg * 32 + tt) << 11;   // tile offset (2048 el)
        ev_ = *(const f16x8*)(Eb + jj);
        fv_ = *(const f16x8*)(Fb + jj);
#pragma unroll
        for (int ot = 0; ot < 4; ++ot)
            b_[ot] = *(const f16x8*)(whh + jb + (ot * 16 + row16) * 32 + quad * 8);
#pragma unroll
        for (int g = 0; g < 4; ++g)
            m_[g] = lmask[mbase + g * 2112 + tt];
    };

    auto COMP = [&](const f16x8& ev_, const f16x8& fv_,
                    const f16x8* b_, const unsigned* m_) {
        union { f16x8 v8; f16x2 h2[4]; } evu, fvu;
        evu.v8 = ev_; fvu.v8 = fv_;
#pragma unroll
        for (int g = 0; g < 4; ++g) {
            unsigned mb = m_[g] >> shl;   // bits 0..7
            union { f16x8 v8; unsigned w[4]; } au;
#pragma unroll
            for (int kk = 0; kk < 4; ++kk) {
                f16x2 t0 = evu.h2[kk] * Es2[g];
                f16x2 t1 = fvu.h2[kk] * Fs2[g];
                f16x2 p2 = __builtin_elementwise_max(t0, t1);
                unsigned lo = (unsigned)__builtin_amdgcn_sbfe((int)mb, 2 * kk, 1);
                unsigned hi = (unsigned)__builtin_amdgcn_sbfe((int)mb, 2 * kk + 1, 1);
                unsigned w  = (lo & 0xFFFFu) | (hi & 0xFFFF0000u);
                unsigned pw = __builtin_bit_cast(unsigned, p2) & w;
                f16x2 mp2   = __builtin_bit_cast(f16x2, pw);
                au.w[kk] = pw;
#if __has_builtin(__builtin_amdgcn_fdot2)
                lsum[g] = __builtin_amdgcn_fdot2(mp2, ones2, lsum[g], false);
#else
                lsum[g] += (float)mp2[0] + (float)mp2[1];
#endif
            }
            __builtin_amdgcn_s_setprio(1);
#pragma unroll
            for (int ot = 0; ot < 4; ++ot)
                acc[g][ot] = __builtin_amdgcn_mfma_f32_16x16x32_f16(au.v8, b_[ot], acc[g][ot], 0, 0, 0);
            __builtin_amdgcn_s_setprio(0);
        }
    };

    // stagger: seg phase + block parity (co-resident waves desync vmem bursts)
    int t0 = ((seg * 8) + ((tile & 1) << 2)) & 31;
    f16x8 evA, fvA, bA[4]; unsigned mA[4];
    f16x8 evB, fvB, bB[4]; unsigned mB[4];
    LOAD(evA, fvA, bA, mA, t0);

#pragma unroll 1
    for (int i = 0; i < 16; ++i) {
        const int t1 = (t0 + 1) & 31;
        LOAD(evB, fvB, bB, mB, t1);
        COMP(evA, fvA, bA, mA);
        const int t2 = (t0 + 2) & 31;
        LOAD(evA, fvA, bA, mA, t2);     // last one (i=15) is redundant, harmless
        COMP(evB, fvB, bB, mB);
        t0 = t2;
    }

    // complete per-row sums across the 4 quads (disjoint k coverage)
#pragma unroll
    for (int g = 0; g < 4; ++g) {
        lsum[g] += __shfl_xor(lsum[g], 16);
        lsum[g] += __shfl_xor(lsum[g], 32);
    }

    __syncthreads();   // mask reads done; st[] may be reused as stash

    auto stash = [&](int buf) {
#pragma unroll
        for (int g = 0; g < 4; ++g)
#pragma unroll
            for (int ot = 0; ot < 4; ++ot)
#pragma unroll
                for (int r = 0; r < 4; ++r)
                    st[buf][(g * 16 + quad * 4 + r) * 68 + ot * 16 + row16] = acc[g][ot][r];
        if (quad == 0)
#pragma unroll
            for (int g = 0; g < 4; ++g)
                lds_l[buf][g * 16 + row16] = lsum[g];
    };
    auto addin = [&](int buf) {
#pragma unroll
        for (int g = 0; g < 4; ++g) {
#pragma unroll
            for (int ot = 0; ot < 4; ++ot)
#pragma unroll
                for (int r = 0; r < 4; ++r)
                    acc[g][ot][r] += st[buf][(g * 16 + quad * 4 + r) * 68 + ot * 16 + row16];
            lsum[g] += lds_l[buf][g * 16 + row16];
        }
    };

    if (seg == 1) stash(0);
    if (seg == 3) stash(1);
    __syncthreads();
    if (seg == 0) addin(0);
    if (seg == 2) addin(1);
    __syncthreads();
    if (seg == 2) stash(0);
    __syncthreads();
    if (seg == 0) {
        addin(0);
        // epilogue: divide by l, ELU, deposit final 64x64 tile into st[0]
#pragma unroll
        for (int g = 0; g < 4; ++g)
#pragma unroll
            for (int r = 0; r < 4; ++r) {
                int   qr  = quad * 4 + r;
                float l   = __shfl(lsum[g], qr);    // lane qr holds row qr's sum
                float rl  = 1.0f / l;
#pragma unroll
                for (int ot = 0; ot < 4; ++ot) {
                    float v = acc[g][ot][r] * rl;
                    float y = v > 0.f ? v : __expf(v) - 1.f;
                    st[0][(g * 16 + qr) * 68 + ot * 16 + row16] = y;
                }
            }
    }
    __syncthreads();
    // cooperative coalesced store: 1024 float4s by 256 threads (nontemporal)
#pragma unroll
    for (int p = 0; p < 4; ++p) {
        int f    = tid + p * 256;
        int row  = f >> 4;
        int col4 = (f & 15) * 4;
        f32x4 v = *(const f32x4*)&st[0][row * 68 + col4];
        __builtin_nontemporal_store(
            v, (f32x4*)&out[(size_t)(tile * 64 + row) * (HH * FOUT) + h * FOUT + col4]);
    }
}

// ---------------------------------------------------------------------------
extern "C" void kernel_launch(void* const* d_in, const int* in_sizes, int n_in,
                              void* d_out, int out_size, void* d_ws, size_t ws_size,
                              hipStream_t stream) {
    const float* features = (const float*)d_in[0];
    int*         adj      = (int*)d_in[1];
    const float* W        = (const float*)d_in[2];
    const float* a_src    = (const float*)d_in[3];
    const float* a_dst    = (const float*)d_in[4];
    float*       out      = (float*)d_out;

    char* ws = (char*)d_ws;
    __hip_bfloat16* WT   = (__hip_bfloat16*)(ws);                             // 512 KB (tiled)
    unsigned short* WhT  = (unsigned short*)(ws + (512 << 10));               // 4 MB (f16, tiled)
    float*          srcv = (float*)(ws + (512 << 10) + (4 << 20));            // 128 KB
    unsigned short* Ebf  = (unsigned short*)(ws + (512 << 10) + (4 << 20) + (128 << 10));  // 64 KB (f16)
    unsigned short* Fbf  = (unsigned short*)(ws + (512 << 10) + (4 << 20) + (192 << 10));  // 64 KB (f16)

    // packed mask: 2 MB in ws if it fits (keeps adj read-only); else in-place.
    const size_t mask_off = (512 << 10) + (4 << 20) + (256 << 10);            // 4.75 MB
    unsigned* maskp; int mstride;
    if (ws_size >= mask_off + (2u << 20)) {
        maskp   = (unsigned*)(ws + mask_off);
        mstride = 256;                         // contiguous: 256 dwords / row-pair
    } else {
        maskp   = (unsigned*)adj;              // in-place fallback (old layout)
        mstride = 8192;
    }

    k_transpose_w<<<dim3(64), 256, 0, stream>>>(W, WT);
    k_prep<<<dim3(2048 + 256), 256, 0, stream>>>(adj, maskp, mstride,
                                                 features, WT, a_src, a_dst,
                                                 WhT, srcv, Ebf, Fbf);
    k_flash<<<dim3(64, 8), 256, 0, stream>>>(maskp, mstride, srcv, Ebf, Fbf,
                                             WhT, out);
}

// Round 12
// 143.850 us; speedup vs baseline: 1.0476x; 1.0476x over previous
//
#include <hip/hip_runtime.h>
#include <hip/hip_bf16.h>

typedef __bf16 bf16x8 __attribute__((ext_vector_type(8)));
typedef _Float16 f16x8 __attribute__((ext_vector_type(8)));
typedef _Float16 f16x2 __attribute__((ext_vector_type(2)));
typedef float  f32x4  __attribute__((ext_vector_type(4)));
typedef unsigned short u16x8 __attribute__((ext_vector_type(8)));
typedef unsigned short us4   __attribute__((ext_vector_type(4)));

#define HH    8
#define NN    4096
#define FIN   512
#define FOUT  64
#define ALPHA 0.2f

// ---------------------------------------------------------------------------
// R23 NOTE: this is the R6 configuration resubmitted VERBATIM — the measured
// best of the session (143.3 µs total). Rounds 7-11 tested five independent
// theories for k_flash's residual (prefetch depth, wave count, LDS issue
// count, XCD affinity, nt cache hints); every one regressed 2-11 µs. The
// remaining gap is structural dependency-stall at grid-capped 2 waves/SIMD;
// ~85 µs of the total is harness-side workspace fill running at 80% of HBM
// peak (its own roofline, not kernel-addressable).
// ---------------------------------------------------------------------------

// ---------------------------------------------------------------------------
// k0: W[h][f][o] (fp32) -> WT2 TILED bf16: [h][kb][o][km], f = kb*32+km.
// Tiled so k_prep's b-loads are contiguous-1KB per instruction.
// ---------------------------------------------------------------------------
__global__ __launch_bounds__(256) void k_transpose_w(
    const float* __restrict__ Wsrc, __hip_bfloat16* __restrict__ WT) {
    __shared__ __hip_bfloat16 lt[64][65];
    const int h  = blockIdx.x >> 3;
    const int f0 = (blockIdx.x & 7) * 64;
    const int tid = threadIdx.x;
#pragma unroll
    for (int p = 0; p < 16; ++p) {
        int f = p * 4 + (tid >> 6);
        int o = tid & 63;
        lt[f][o] = __float2bfloat16(Wsrc[((size_t)h * FIN + f0 + f) * FOUT + o]);
    }
    __syncthreads();
#pragma unroll
    for (int p = 0; p < 16; ++p) {
        int o = p * 4 + (tid >> 6);
        int f = tid & 63;          // local f; global f = f0 + f
        int gf = f0 + f;
        // WT2[h][kb][o][km]: ((h*16 + gf/32)*64 + o)*32 + gf%32
        WT[(((size_t)h * 16 + (gf >> 5)) * 64 + o) * 32 + (gf & 31)] = lt[f][o];
    }
}

// ---------------------------------------------------------------------------
// k_prep: FUSED adjacency bit-pack + projection.
// Pack: lane-contiguous int4 loads (wave = 4 KB contiguous) + shfl_xor
// OR-tree + LDS scatter + coalesced 1KB store. Projection: tiled WT2 reads
// (contiguous 1 KB per inst), tiled WhT stores, f16 outputs. Projection
// blocks dispatched FIRST (blockIdx < 256) to overlap the pack wave.
// ---------------------------------------------------------------------------
__global__ __launch_bounds__(256) void k_prep(
    const int* __restrict__ adj,
    unsigned* __restrict__ maskdst, int mstride,
    const float* __restrict__ feat,
    const __hip_bfloat16* __restrict__ WT,
    const float* __restrict__ a_src,
    const float* __restrict__ a_dst,
    unsigned short* __restrict__ WhT,
    float* __restrict__ srcv,
    unsigned short* __restrict__ Ebf, unsigned short* __restrict__ Fbf) {
    __shared__ alignas(16) __hip_bfloat16 lfeat[32][520];

    const int tid = threadIdx.x;

    if (blockIdx.x >= 256) {   // ---- pack path ----
        const int b = blockIdx.x - 256;
        const size_t base = (size_t)b * 8192;
        unsigned* lbuf = (unsigned*)&lfeat[0][0];    // 1 KB alias
        const int l = tid & 63;
        const int w = tid >> 6;
        unsigned keep = 0;
#pragma unroll
        for (int i = 0; i < 8; ++i) {
            int4 v = *(const int4*)(adj + base + (size_t)(i * 256 + tid) * 4);
            unsigned nib = (unsigned)(v.x > 0) | ((unsigned)(v.y > 0) << 1)
                         | ((unsigned)(v.z > 0) << 2) | ((unsigned)(v.w > 0) << 3);
            unsigned vv = nib << ((l & 7) * 4);
            vv |= __shfl_xor(vv, 1);
            vv |= __shfl_xor(vv, 2);
            vv |= __shfl_xor(vv, 4);
            keep = ((l & 7) == i) ? vv : keep;
        }
        // lane l holds dword (i = l&7, d = l>>3): index = (l&7)*32 + w*8 + (l>>3)
        lbuf[(l & 7) * 32 + w * 8 + (l >> 3)] = keep;
        __syncthreads();
        maskdst[(size_t)b * mstride + tid] = lbuf[tid];
        return;
    }

    // ---- projection path ----
    const int pb   = blockIdx.x;
    const int tile = pb & 127;            // 32 rows per block
    const int hgy  = pb >> 7;             // 0..1

#pragma unroll
    for (int p = 0; p < 16; ++p) {
        int idx  = p * 256 + tid;
        int row  = idx >> 7;
        int col4 = (idx & 127) * 4;
        float4 f = *(const float4*)(feat + (size_t)(tile * 32 + row) * FIN + col4);
        __hip_bfloat16* dst = &lfeat[row][col4];
        dst[0] = __float2bfloat16(f.x); dst[1] = __float2bfloat16(f.y);
        dst[2] = __float2bfloat16(f.z); dst[3] = __float2bfloat16(f.w);
    }
    __syncthreads();

    const int h     = hgy * 4 + (tid >> 6);
    const int lane  = tid & 63;
    const int row16 = lane & 15;
    const int quad  = lane >> 4;

    // tiled WT2 base for head h: 16 kb-tiles x 2048 elements
    const unsigned short* WTu = (const unsigned short*)WT + (size_t)h * 16 * 2048;

    f32x4 acc[2][4] = {};
    for (int k0 = 0; k0 < FIN; k0 += 32) {
        bf16x8 a0 = *(const bf16x8*)&lfeat[row16][k0 + quad * 8];
        bf16x8 a1 = *(const bf16x8*)&lfeat[16 + row16][k0 + quad * 8];
        const unsigned short* wkb = WTu + (size_t)(k0 >> 5) * 2048;
#pragma unroll
        for (int ot = 0; ot < 4; ++ot) {
            bf16x8 b = *(const bf16x8*)(wkb + (ot * 16 + row16) * 32 + quad * 8);
            acc[0][ot] = __builtin_amdgcn_mfma_f32_16x16x32_bf16(a0, b, acc[0][ot], 0, 0, 0);
            acc[1][ot] = __builtin_amdgcn_mfma_f32_16x16x32_bf16(a1, b, acc[1][ot], 0, 0, 0);
        }
    }

    // tiled WhT store: [h][jb=tile][o][jm], jm = g*16 + quad*4 + r
#pragma unroll
    for (int g = 0; g < 2; ++g)
#pragma unroll
        for (int ot = 0; ot < 4; ++ot) {
            us4 u;
#pragma unroll
            for (int r = 0; r < 4; ++r)
                u[r] = __builtin_bit_cast(unsigned short, (_Float16)acc[g][ot][r]);
            *(us4*)(WhT + (((size_t)(h * 128 + tile) * 64 + ot * 16 + row16) << 5)
                        + g * 16 + quad * 4) = u;
        }

    float asv[4], adv[4];
#pragma unroll
    for (int ot = 0; ot < 4; ++ot) {
        asv[ot] = a_src[h * FOUT + ot * 16 + row16];
        adv[ot] = a_dst[h * FOUT + ot * 16 + row16];
    }
#pragma unroll
    for (int g = 0; g < 2; ++g)
#pragma unroll
        for (int r = 0; r < 4; ++r) {
            float ss = 0.f, dd = 0.f;
#pragma unroll
            for (int ot = 0; ot < 4; ++ot) {
                ss += acc[g][ot][r] * asv[ot];
                dd += acc[g][ot][r] * adv[ot];
            }
            ss += __shfl_xor(ss, 1); ss += __shfl_xor(ss, 2);
            ss += __shfl_xor(ss, 4); ss += __shfl_xor(ss, 8);
            dd += __shfl_xor(dd, 1); dd += __shfl_xor(dd, 2);
            dd += __shfl_xor(dd, 4); dd += __shfl_xor(dd, 8);
            if (row16 == 0) {
                int n = tile * 32 + g * 16 + quad * 4 + r;
                srcv[h * NN + n] = ss;
                _Float16 e = (_Float16)__expf(dd);
                _Float16 f = (_Float16)__expf(ALPHA * dd);
                Ebf[h * NN + n] = __builtin_bit_cast(unsigned short, e);
                Fbf[h * NN + n] = __builtin_bit_cast(unsigned short, f);
            }
        }
}

// ---------------------------------------------------------------------------
// k_flash v6 (R6, proven best): packed-f16 masked softmax attention + ELU,
// coalesced tiled-WhT b-loads, ping-pong 1-deep prefetch, seg+parity
// stagger, setprio around MFMA. 256 thr = 4 waves = 4 j-segs x 1024 j;
// 64-row tiles; grid (64,8); acc[4][4] = 64 AGPR; LDS 35328 B.
// p = exp(LeakyReLU(s+d)) = max(Es*Ed, Fs*Fd) (exp monotone, exact);
// lsum accumulated via fdot2 on the masked packed pair.
// ---------------------------------------------------------------------------
__global__ __launch_bounds__(256, 3) void k_flash(
    const unsigned* __restrict__ maskp, int mstride,
    const float* __restrict__ srcv,
    const unsigned short* __restrict__ Ebf,
    const unsigned short* __restrict__ Fbf,
    const unsigned short* __restrict__ WhT,
    float* __restrict__ out) {
    __shared__ float st[2][64 * 68];     // 34816 B; mask (33792 B) aliases st
    __shared__ float lds_l[2][64];

    unsigned* lmask = (unsigned*)&st[0][0];   // [64 rows][132 dwords]

    const int tid   = threadIdx.x;
    const int seg   = tid >> 6;               // 0..3, 1024 j each
    const int lane  = tid & 63;
    const int row16 = lane & 15;
    const int quad  = lane >> 4;
    const int shl   = quad * 8;
    const int tile  = blockIdx.x;             // 64 rows
    const int h     = blockIdx.y;

    // ---- stage mask bits for 64 rows (32 row-pair chunks, 1 KB each)
#pragma unroll
    for (int p = 0; p < 8; ++p) {
        int tt = tid + p * 256;
        int c  = tt >> 6;                     // chunk 0..31
        int o  = (tt & 63) * 16;              // byte offset in chunk
        int4 v = *(const int4*)((const char*)maskp
                                + ((size_t)(tile * 32 + c) * mstride) * 4 + o);
        int row = c * 2 + (o >> 9);
        int dw  = (o & 511) >> 2;
        *(int4*)&lmask[row * 132 + dw] = v;
    }
    __syncthreads();

    // per-row src factors, packed f16x2 (both halves equal)
    f16x2 Es2[4], Fs2[4];
#pragma unroll
    for (int g = 0; g < 4; ++g) {
        float si = srcv[h * NN + tile * 64 + g * 16 + row16];
        _Float16 e = (_Float16)__expf(si);
        _Float16 f = (_Float16)__expf(ALPHA * si);
        Es2[g][0] = e; Es2[g][1] = e;
        Fs2[g][0] = f; Fs2[g][1] = f;
    }
    const int mbase = row16 * 132 + seg * 32;   // + g*2112 + t

    const unsigned short* Eb  = Ebf + h * NN + seg * 1024;
    const unsigned short* Fb  = Fbf + h * NN + seg * 1024;
    const unsigned short* whh = WhT + (size_t)h * FOUT * NN;   // tiled base

    f32x4 acc[4][4] = {};
    float lsum[4]   = {};
    const f16x2 ones2 = {(_Float16)1.0f, (_Float16)1.0f};

    auto LOAD = [&](f16x8& ev_, f16x8& fv_, f16x8* b_, unsigned* m_, int tt) {
        const int jj = tt * 32 + shl;
        const size_t jb = (size_t)(seg * 32 + tt) << 11;   // tile offset (2048 el)
        ev_ = *(const f16x8*)(Eb + jj);
        fv_ = *(const f16x8*)(Fb + jj);
#pragma unroll
        for (int ot = 0; ot < 4; ++ot)
            b_[ot] = *(const f16x8*)(whh + jb + (ot * 16 + row16) * 32 + quad * 8);
#pragma unroll
        for (int g = 0; g < 4; ++g)
            m_[g] = lmask[mbase + g * 2112 + tt];
    };

    auto COMP = [&](const f16x8& ev_, const f16x8& fv_,
                    const f16x8* b_, const unsigned* m_) {
        union { f16x8 v8; f16x2 h2[4]; } evu, fvu;
        evu.v8 = ev_; fvu.v8 = fv_;
#pragma unroll
        for (int g = 0; g < 4; ++g) {
            unsigned mb = m_[g] >> shl;   // bits 0..7
            union { f16x8 v8; unsigned w[4]; } au;
#pragma unroll
            for (int kk = 0; kk < 4; ++kk) {
                f16x2 t0 = evu.h2[kk] * Es2[g];
                f16x2 t1 = fvu.h2[kk] * Fs2[g];
                f16x2 p2 = __builtin_elementwise_max(t0, t1);
                unsigned lo = (unsigned)__builtin_amdgcn_sbfe((int)mb, 2 * kk, 1);
                unsigned hi = (unsigned)__builtin_amdgcn_sbfe((int)mb, 2 * kk + 1, 1);
                unsigned w  = (lo & 0xFFFFu) | (hi & 0xFFFF0000u);
                unsigned pw = __builtin_bit_cast(unsigned, p2) & w;
                f16x2 mp2   = __builtin_bit_cast(f16x2, pw);
                au.w[kk] = pw;
#if __has_builtin(__builtin_amdgcn_fdot2)
                lsum[g] = __builtin_amdgcn_fdot2(mp2, ones2, lsum[g], false);
#else
                lsum[g] += (float)mp2[0] + (float)mp2[1];
#endif
            }
            __builtin_amdgcn_s_setprio(1);
#pragma unroll
            for (int ot = 0; ot < 4; ++ot)
                acc[g][ot] = __builtin_amdgcn_mfma_f32_16x16x32_f16(au.v8, b_[ot], acc[g][ot], 0, 0, 0);
            __builtin_amdgcn_s_setprio(0);
        }
    };

    // stagger: seg phase + block parity (co-resident waves have same seg)
    int t0 = ((seg * 8) + ((tile & 1) << 2)) & 31;
    f16x8 evA, fvA, bA[4]; unsigned mA[4];
    f16x8 evB, fvB, bB[4]; unsigned mB[4];
    LOAD(evA, fvA, bA, mA, t0);

#pragma unroll 1
    for (int i = 0; i < 16; ++i) {
        const int t1 = (t0 + 1) & 31;
        LOAD(evB, fvB, bB, mB, t1);
        COMP(evA, fvA, bA, mA);
        const int t2 = (t0 + 2) & 31;
        LOAD(evA, fvA, bA, mA, t2);     // last one (i=15) is redundant, harmless
        COMP(evB, fvB, bB, mB);
        t0 = t2;
    }

    // complete per-row sums across the 4 quads (disjoint k coverage)
#pragma unroll
    for (int g = 0; g < 4; ++g) {
        lsum[g] += __shfl_xor(lsum[g], 16);
        lsum[g] += __shfl_xor(lsum[g], 32);
    }

    __syncthreads();   // mask reads done; st[] may be reused as stash

    auto stash = [&](int buf) {
#pragma unroll
        for (int g = 0; g < 4; ++g)
#pragma unroll
            for (int ot = 0; ot < 4; ++ot)
#pragma unroll
                for (int r = 0; r < 4; ++r)
                    st[buf][(g * 16 + quad * 4 + r) * 68 + ot * 16 + row16] = acc[g][ot][r];
        if (quad == 0)
#pragma unroll
            for (int g = 0; g < 4; ++g)
                lds_l[buf][g * 16 + row16] = lsum[g];
    };
    auto addin = [&](int buf) {
#pragma unroll
        for (int g = 0; g < 4; ++g) {
#pragma unroll
            for (int ot = 0; ot < 4; ++ot)
#pragma unroll
                for (int r = 0; r < 4; ++r)
                    acc[g][ot][r] += st[buf][(g * 16 + quad * 4 + r) * 68 + ot * 16 + row16];
            lsum[g] += lds_l[buf][g * 16 + row16];
        }
    };

    if (seg == 1) stash(0);
    if (seg == 3) stash(1);
    __syncthreads();
    if (seg == 0) addin(0);
    if (seg == 2) addin(1);
    __syncthreads();
    if (seg == 2) stash(0);
    __syncthreads();
    if (seg == 0) {
        addin(0);
        // epilogue: divide by l, ELU, deposit final 64x64 tile into st[0]
#pragma unroll
        for (int g = 0; g < 4; ++g)
#pragma unroll
            for (int r = 0; r < 4; ++r) {
                int   qr  = quad * 4 + r;
                float l   = __shfl(lsum[g], qr);    // lane qr holds row qr's sum
                float rl  = 1.0f / l;
#pragma unroll
                for (int ot = 0; ot < 4; ++ot) {
                    float v = acc[g][ot][r] * rl;
                    float y = v > 0.f ? v : __expf(v) - 1.f;
                    st[0][(g * 16 + qr) * 68 + ot * 16 + row16] = y;
                }
            }
    }
    __syncthreads();
    // cooperative coalesced store: 1024 float4s by 256 threads
#pragma unroll
    for (int p = 0; p < 4; ++p) {
        int f    = tid + p * 256;
        int row  = f >> 4;
        int col4 = (f & 15) * 4;
        float4 v = *(const float4*)&st[0][row * 68 + col4];
        *(float4*)&out[(size_t)(tile * 64 + row) * (HH * FOUT) + h * FOUT + col4] = v;
    }
}

// ---------------------------------------------------------------------------
extern "C" void kernel_launch(void* const* d_in, const int* in_sizes, int n_in,
                              void* d_out, int out_size, void* d_ws, size_t ws_size,
                              hipStream_t stream) {
    const float* features = (const float*)d_in[0];
    int*         adj      = (int*)d_in[1];
    const float* W        = (const float*)d_in[2];
    const float* a_src    = (const float*)d_in[3];
    const float* a_dst    = (const float*)d_in[4];
    float*       out      = (float*)d_out;

    char* ws = (char*)d_ws;
    __hip_bfloat16* WT   = (__hip_bfloat16*)(ws);                             // 512 KB (tiled)
    unsigned short* WhT  = (unsigned short*)(ws + (512 << 10));               // 4 MB (f16, tiled)
    float*          srcv = (float*)(ws + (512 << 10) + (4 << 20));            // 128 KB
    unsigned short* Ebf  = (unsigned short*)(ws + (512 << 10) + (4 << 20) + (128 << 10));  // 64 KB (f16)
    unsigned short* Fbf  = (unsigned short*)(ws + (512 << 10) + (4 << 20) + (192 << 10));  // 64 KB (f16)

    // packed mask: 2 MB in ws if it fits (keeps adj read-only); else in-place.
    const size_t mask_off = (512 << 10) + (4 << 20) + (256 << 10);            // 4.75 MB
    unsigned* maskp; int mstride;
    if (ws_size >= mask_off + (2u << 20)) {
        maskp   = (unsigned*)(ws + mask_off);
        mstride = 256;                         // contiguous: 256 dwords / row-pair
    } else {
        maskp   = (unsigned*)adj;              // in-place fallback (old layout)
        mstride = 8192;
    }

    k_transpose_w<<<dim3(64), 256, 0, stream>>>(W, WT);
    k_prep<<<dim3(2048 + 256), 256, 0, stream>>>(adj, maskp, mstride,
                                                 features, WT, a_src, a_dst,
                                                 WhT, srcv, Ebf, Fbf);
    k_flash<<<dim3(64, 8), 256, 0, stream>>>(maskp, mstride, srcv, Ebf, Fbf,
                                             WhT, out);
}